// Round 1
// baseline (1322.552 us; speedup 1.0000x reference)
//
#include <hip/hip_runtime.h>
#include <cmath>

#define EPSF 1e-7f

constexpr int B_ = 4, S_ = 1024, E_ = 1024, H_ = 16, D_ = 64;
constexpr int BS_ = B_ * S_;   // 4096 rows per matrix

// ---------------- kernel 1: per-row lambda of the three inputs ----------------
__global__ __launch_bounds__(256) void row_lam_kernel(
    const float* __restrict__ xq, const float* __restrict__ xk,
    const float* __restrict__ xv, float* __restrict__ lamRow) {
  int row = blockIdx.x * 4 + (threadIdx.x >> 6);   // 4 rows per block (1 wave each)
  int lane = threadIdx.x & 63;
  const float* x = (row < BS_) ? xq : (row < 2 * BS_ ? xk : xv);
  int r = row & (BS_ - 1);
  const float4* xr = (const float4*)(x + (size_t)r * E_);
  float s = 0.f;
  #pragma unroll
  for (int i = 0; i < 4; i++) {
    float4 t = xr[lane + i * 64];
    s += t.x * t.x + t.y * t.y + t.z * t.z + t.w * t.w;
  }
  #pragma unroll
  for (int m = 1; m < 64; m <<= 1) s += __shfl_xor(s, m, 64);
  if (lane == 0) lamRow[row] = 2.0f / fmaxf(1.0f - s, EPSF);
}

// ---------------- kernel 2: column norms of z, cosh/sinh of 2*bias ----------------
__global__ __launch_bounds__(256) void col_stats_kernel(
    const float* __restrict__ zq, const float* __restrict__ zk, const float* __restrict__ zv,
    const float* __restrict__ bq, const float* __restrict__ bk, const float* __restrict__ bv,
    float* __restrict__ znA, float* __restrict__ chA, float* __restrict__ shA) {
  int mat = blockIdx.x >> 4;             // 16 blocks of 64 cols per matrix
  int c0 = (blockIdx.x & 15) * 64;
  const float* z = mat == 0 ? zq : (mat == 1 ? zk : zv);
  const float* bb = mat == 0 ? bq : (mat == 1 ? bk : bv);
  int col = c0 + (threadIdx.x & 63);
  int r0 = threadIdx.x >> 6;
  float s = 0.f;
  for (int rr = r0; rr < E_; rr += 4) {
    float t = z[(size_t)rr * E_ + col];
    s += t * t;
  }
  __shared__ float red[4][64];
  red[r0][threadIdx.x & 63] = s;
  __syncthreads();
  if (r0 == 0) {
    int l = threadIdx.x;
    s = red[0][l] + red[1][l] + red[2][l] + red[3][l];
    float n = fmaxf(sqrtf(s), 1e-15f);
    int idx = mat * E_ + col;
    znA[idx] = n;
    float rb = bb[col];
    chA[idx] = coshf(2.f * rb);
    shA[idx] = sinhf(2.f * rb);
  }
}

// ---------------- kernel 3: xz GEMM + hlinear epilogue (pre-normalization w) ----------------
// 128x128 tile, BK=8, 256 threads, 8x8 microtile split as 2x2 blocks of 4x4 (bank-friendly)
__global__ __launch_bounds__(256) void hlinear_gemm_kernel(
    const float* __restrict__ xq, const float* __restrict__ xk, const float* __restrict__ xv,
    const float* __restrict__ zq, const float* __restrict__ zk, const float* __restrict__ zv,
    const float* __restrict__ lamRow, const float* __restrict__ znA,
    const float* __restrict__ chA, const float* __restrict__ shA,
    float* __restrict__ W) {
  const int mat = blockIdx.z;
  const float* x = mat == 0 ? xq : (mat == 1 ? xk : xv);
  const float* z = mat == 0 ? zq : (mat == 1 ? zk : zv);
  const int m0 = blockIdx.y * 128, n0 = blockIdx.x * 128;
  __shared__ float As[8][128];   // [k][m]
  __shared__ float Bs[8][128];   // [k][n]
  const int tid = threadIdx.x;
  const int tx = tid & 15, ty = tid >> 4;
  float acc[8][8];
  #pragma unroll
  for (int i = 0; i < 8; i++)
    #pragma unroll
    for (int j = 0; j < 8; j++) acc[i][j] = 0.f;
  const int arow = tid >> 1, acol = (tid & 1) * 4;
  const int brow = tid >> 5, bcol = (tid & 31) * 4;
  const float* aptr = x + (size_t)(m0 + arow) * E_ + acol;
  const float* bptr = z + (size_t)brow * E_ + n0 + bcol;
  for (int k0 = 0; k0 < E_; k0 += 8) {
    float4 av = *(const float4*)(aptr + k0);
    float4 bv = *(const float4*)(bptr + (size_t)k0 * E_);
    __syncthreads();
    As[acol + 0][arow] = av.x;
    As[acol + 1][arow] = av.y;
    As[acol + 2][arow] = av.z;
    As[acol + 3][arow] = av.w;
    *(float4*)&Bs[brow][bcol] = bv;
    __syncthreads();
    #pragma unroll
    for (int k = 0; k < 8; k++) {
      float4 a0 = *(const float4*)&As[k][ty * 4];
      float4 a1 = *(const float4*)&As[k][64 + ty * 4];
      float4 b0 = *(const float4*)&Bs[k][tx * 4];
      float4 b1 = *(const float4*)&Bs[k][64 + tx * 4];
      float a[8] = {a0.x, a0.y, a0.z, a0.w, a1.x, a1.y, a1.z, a1.w};
      float bb[8] = {b0.x, b0.y, b0.z, b0.w, b1.x, b1.y, b1.z, b1.w};
      #pragma unroll
      for (int i = 0; i < 8; i++)
        #pragma unroll
        for (int j = 0; j < 8; j++) acc[i][j] += a[i] * bb[j];
    }
  }
  const float* lamP = lamRow + mat * BS_ + m0;
  const int cbase = mat * E_ + n0;
  float* out = W + (size_t)mat * BS_ * E_;
  #pragma unroll
  for (int i = 0; i < 8; i++) {
    int mr = (i < 4) ? ty * 4 + i : 64 + ty * 4 + (i - 4);
    float lam = lamP[mr];
    #pragma unroll
    for (int j = 0; j < 8; j++) {
      int nc = (j < 4) ? tx * 4 + j : 64 + tx * 4 + (j - 4);
      float zn = znA[cbase + nc];
      float arg = lam * acc[i][j] / zn * chA[cbase + nc] - (lam - 1.f) * shA[cbase + nc];
      float v = 2.f * zn * asinhf(arg);
      out[(size_t)(m0 + mr) * E_ + (n0 + nc)] = sinhf(v);
    }
  }
}

// ---------------- kernel 4: p = w / (1 + sqrt(1 + |w|^2)) per row, in-place ----------------
__global__ __launch_bounds__(256) void normalize_kernel(float* __restrict__ W) {
  float* w = W + (size_t)blockIdx.x * E_;
  int tid = threadIdx.x;
  float4 v = ((float4*)w)[tid];
  float s = v.x * v.x + v.y * v.y + v.z * v.z + v.w * v.w;
  #pragma unroll
  for (int m = 1; m < 64; m <<= 1) s += __shfl_xor(s, m, 64);
  __shared__ float red[4];
  if ((tid & 63) == 0) red[tid >> 6] = s;
  __syncthreads();
  s = red[0] + red[1] + red[2] + red[3];
  float t = 1.f / (1.f + sqrtf(1.f + s));
  v.x *= t; v.y *= t; v.z *= t; v.w *= t;
  ((float4*)w)[tid] = v;
}

// ---------------- kernel 5: flash-style hyperbolic attention + midpoint + logmap0*scale ----------------
// grid (S/64, H, B), 256 threads. Q-tile 64 rows, K/V-tile 32 keys. thread = (r = tid>>2, sub = tid&3)
__global__ __launch_bounds__(256) void attention_kernel(
    const float* __restrict__ P, float* __restrict__ TV, float scale) {
  const int qt = blockIdx.x, h = blockIdx.y, b = blockIdx.z;
  const float* pq = P;
  const float* pk = P + (size_t)BS_ * E_;
  const float* pv = P + (size_t)2 * BS_ * E_;
  const int tid = threadIdx.x;
  const int r = tid >> 2, sub = tid & 3;

  __shared__ float qs[64][68];
  __shared__ float ks[32][68];
  __shared__ float vs[32][68];
  __shared__ float es[64][33];
  __shared__ float q2s[64];
  __shared__ float k2s[32], lamLs[32], lamMs[32];

  // load Q tile (64 x 64)
  {
    int lr = tid >> 2, lc = (tid & 3) * 16;
    const float4* src = (const float4*)(pq + ((size_t)(b * S_ + qt * 64 + lr)) * E_ + h * 64 + lc);
    float4* dst = (float4*)&qs[lr][lc];
    #pragma unroll
    for (int i = 0; i < 4; i++) dst[i] = src[i];
  }
  __syncthreads();
  // per-query head-norm q2
  {
    float s = 0.f;
    #pragma unroll
    for (int i = 0; i < 16; i++) { float t = qs[r][sub * 16 + i]; s += t * t; }
    s += __shfl_xor(s, 1, 64);
    s += __shfl_xor(s, 2, 64);
    if (sub == 0) q2s[r] = s;
  }
  // preload own q row into registers (16 float4 = 64 floats)
  float4 qreg[16];
  {
    const float4* qrow = (const float4*)&qs[r][0];
    #pragma unroll
    for (int i = 0; i < 16; i++) qreg[i] = qrow[i];
  }
  __syncthreads();
  const float q2 = q2s[r];

  float m_prev = -INFINITY;
  float dnm = 0.f;
  float accN[16];
  #pragma unroll
  for (int i = 0; i < 16; i++) accN[i] = 0.f;

  for (int kt = 0; kt < S_ / 32; ++kt) {
    __syncthreads();   // protect ks/vs/es from previous iteration readers
    // load K,V tile (32 x 64)
    {
      int lr = tid >> 3, lc = (tid & 7) * 8;
      size_t rowoff = ((size_t)(b * S_ + kt * 32 + lr)) * E_ + h * 64 + lc;
      const float4* srck = (const float4*)(pk + rowoff);
      const float4* srcv = (const float4*)(pv + rowoff);
      float4* dk = (float4*)&ks[lr][lc];
      float4* dv = (float4*)&vs[lr][lc];
      dk[0] = srck[0]; dk[1] = srck[1];
      dv[0] = srcv[0]; dv[1] = srcv[1];
    }
    __syncthreads();
    // per-key head-norm k2 and value conformal factor lam
    {
      int kr = tid >> 3, s8 = tid & 7;
      float sk = 0.f, sv = 0.f;
      #pragma unroll
      for (int i = 0; i < 8; i++) {
        float t = ks[kr][s8 * 8 + i]; sk += t * t;
        float u = vs[kr][s8 * 8 + i]; sv += u * u;
      }
      #pragma unroll
      for (int m = 1; m < 8; m <<= 1) {
        sk += __shfl_xor(sk, m, 64);
        sv += __shfl_xor(sv, m, 64);
      }
      if (s8 == 0) {
        k2s[kr] = sk;
        float lam = 2.f / fmaxf(1.f - sv, EPSF);
        lamLs[kr] = lam;
        lamMs[kr] = lam - 1.f;
      }
    }
    __syncthreads();
    // scores: keys kk = 4*j + sub (interleaved to avoid 4-way LDS bank conflicts)
    float sc[8];
    float tmax = -INFINITY;
    #pragma unroll
    for (int j = 0; j < 8; j++) {
      int kk = 4 * j + sub;
      const float4* kp = (const float4*)&ks[kk][0];
      float dot = 0.f;
      #pragma unroll
      for (int d = 0; d < 16; d++) {
        float4 kv = kp[d];
        dot += qreg[d].x * kv.x + qreg[d].y * kv.y + qreg[d].z * kv.z + qreg[d].w * kv.w;
      }
      float k2 = k2s[kk];
      float diff2 = fmaxf(q2 + k2 - 2.f * dot, 0.f);
      float den = fmaxf((1.f - q2) * (1.f - k2), EPSF);
      float ach = fmaxf(1.f + 2.f * diff2 / den, 1.f + 1e-6f);
      float s = -acoshf(ach);
      sc[j] = s;
      tmax = fmaxf(tmax, s);
    }
    tmax = fmaxf(tmax, __shfl_xor(tmax, 1, 64));
    tmax = fmaxf(tmax, __shfl_xor(tmax, 2, 64));
    float m_new = fmaxf(m_prev, tmax);
    float alpha = expf(m_prev - m_new);   // exp(-inf)=0 on first tile
    float dloc = 0.f;
    #pragma unroll
    for (int j = 0; j < 8; j++) {
      int kk = 4 * j + sub;
      float e = expf(sc[j] - m_new);
      es[r][kk] = e;
      dloc += e * lamMs[kk];
    }
    dnm = dnm * alpha + dloc;
    m_prev = m_new;
    __syncthreads();
    // PV: accumulate dims sub*16..+15 over 32 keys (1/l cancels in num/dnm ratio)
    #pragma unroll
    for (int i = 0; i < 16; i++) accN[i] *= alpha;
    for (int k = 0; k < 32; k++) {
      float wl = es[r][k] * lamLs[k];
      const float4* vp = (const float4*)&vs[k][sub * 16];
      #pragma unroll
      for (int d = 0; d < 4; d++) {
        float4 vv = vp[d];
        accN[4 * d + 0] += wl * vv.x;
        accN[4 * d + 1] += wl * vv.y;
        accN[4 * d + 2] += wl * vv.z;
        accN[4 * d + 3] += wl * vv.w;
      }
    }
  }
  // finalize: u = num/dnm (dnm >= 1, clip inactive), midpoint halving, logmap0 * scale
  dnm += __shfl_xor(dnm, 1, 64);
  dnm += __shfl_xor(dnm, 2, 64);
  float u[16];
  float su = 0.f;
  #pragma unroll
  for (int i = 0; i < 16; i++) { u[i] = accN[i] / dnm; su += u[i] * u[i]; }
  su += __shfl_xor(su, 1, 64);
  su += __shfl_xor(su, 2, 64);
  float g = 1.f / (1.f + sqrtf(fmaxf(1.f - su, EPSF)));   // mid = g*u
  float n2 = fmaxf(su * g * g, 1e-15f);
  float n = sqrtf(n2);
  float fac = atanhf(fminf(n, 1.f - 1e-6f)) / n * g * scale;
  float4* out = (float4*)(TV + ((size_t)(b * S_ + qt * 64 + r)) * E_ + h * 64 + sub * 16);
  #pragma unroll
  for (int d = 0; d < 4; d++) {
    float4 o;
    o.x = fac * u[4 * d + 0];
    o.y = fac * u[4 * d + 1];
    o.z = fac * u[4 * d + 2];
    o.w = fac * u[4 * d + 3];
    out[d] = o;
  }
}

// ---------------- kernel 6: expmap0 per full E-row, in-place on d_out ----------------
__global__ __launch_bounds__(256) void expmap_kernel(float* __restrict__ TV) {
  float* w = TV + (size_t)blockIdx.x * E_;
  int tid = threadIdx.x;
  float4 v = ((float4*)w)[tid];
  float s = v.x * v.x + v.y * v.y + v.z * v.z + v.w * v.w;
  #pragma unroll
  for (int m = 1; m < 64; m <<= 1) s += __shfl_xor(s, m, 64);
  __shared__ float red[4];
  if ((tid & 63) == 0) red[tid >> 6] = s;
  __syncthreads();
  s = red[0] + red[1] + red[2] + red[3];
  float n = sqrtf(fmaxf(s, 1e-15f));
  float f = tanhf(n) / n;
  v.x *= f; v.y *= f; v.z *= f; v.w *= f;
  ((float4*)w)[tid] = v;
}

extern "C" void kernel_launch(void* const* d_in, const int* in_sizes, int n_in,
                              void* d_out, int out_size, void* d_ws, size_t ws_size,
                              hipStream_t stream) {
  (void)in_sizes; (void)n_in; (void)out_size; (void)ws_size;
  const float* q  = (const float*)d_in[0];
  const float* k  = (const float*)d_in[1];
  const float* v  = (const float*)d_in[2];
  const float* zq = (const float*)d_in[3];
  const float* bq = (const float*)d_in[4];
  const float* zk = (const float*)d_in[5];
  const float* bk = (const float*)d_in[6];
  const float* zv = (const float*)d_in[7];
  const float* bv = (const float*)d_in[8];

  float* W      = (float*)d_ws;                       // [3][BS][E] = 50.3 MB
  float* lamRow = W + (size_t)3 * BS_ * E_;           // [3*BS]
  float* znA    = lamRow + 3 * BS_;                   // [3*E]
  float* chA    = znA + 3 * E_;                       // [3*E]
  float* shA    = chA + 3 * E_;                       // [3*E]
  float* out    = (float*)d_out;

  // beta-concatenation scale, computed host-side
  double lb1 = lgamma(E_ / 2.0) + lgamma(0.5) - lgamma(E_ / 2.0 + 0.5);
  double lb2 = lgamma(D_ / 2.0) + lgamma(0.5) - lgamma(D_ / 2.0 + 0.5);
  float scale = (float)exp(lb1 - lb2);

  hipLaunchKernelGGL(row_lam_kernel, dim3(3 * BS_ / 4), dim3(256), 0, stream, q, k, v, lamRow);
  hipLaunchKernelGGL(col_stats_kernel, dim3(48), dim3(256), 0, stream,
                     zq, zk, zv, bq, bk, bv, znA, chA, shA);
  hipLaunchKernelGGL(hlinear_gemm_kernel, dim3(E_ / 128, BS_ / 128, 3), dim3(256), 0, stream,
                     q, k, v, zq, zk, zv, lamRow, znA, chA, shA, W);
  hipLaunchKernelGGL(normalize_kernel, dim3(3 * BS_), dim3(256), 0, stream, W);
  hipLaunchKernelGGL(attention_kernel, dim3(S_ / 64, H_, B_), dim3(256), 0, stream, W, out, scale);
  hipLaunchKernelGGL(expmap_kernel, dim3(BS_), dim3(256), 0, stream, out);
}

// Round 2
// 1013.415 us; speedup vs baseline: 1.3050x; 1.3050x over previous
//
#include <hip/hip_runtime.h>
#include <cmath>

#define EPSF 1e-7f

constexpr int B_ = 4, S_ = 1024, E_ = 1024, H_ = 16, D_ = 64;
constexpr int BS_ = B_ * S_;   // 4096 rows per matrix

typedef __attribute__((ext_vector_type(8))) short bf16x8;
typedef __attribute__((ext_vector_type(4))) float f32x4;

__device__ inline unsigned short f2bf(float f) {
  union { float f; unsigned int u; } x; x.f = f;
  unsigned int r = x.u + 0x7fffu + ((x.u >> 16) & 1u);   // RNE
  return (unsigned short)(r >> 16);
}
__device__ inline float bf2f(unsigned short h) {
  union { unsigned int u; float f; } x; x.u = ((unsigned int)h) << 16; return x.f;
}

// ---------------- kernel 1: per-row lambda of the three inputs ----------------
__global__ __launch_bounds__(256) void row_lam_kernel(
    const float* __restrict__ xq, const float* __restrict__ xk,
    const float* __restrict__ xv, float* __restrict__ lamRow) {
  int row = blockIdx.x * 4 + (threadIdx.x >> 6);
  int lane = threadIdx.x & 63;
  const float* x = (row < BS_) ? xq : (row < 2 * BS_ ? xk : xv);
  int r = row & (BS_ - 1);
  const float4* xr = (const float4*)(x + (size_t)r * E_);
  float s = 0.f;
  #pragma unroll
  for (int i = 0; i < 4; i++) {
    float4 t = xr[lane + i * 64];
    s += t.x * t.x + t.y * t.y + t.z * t.z + t.w * t.w;
  }
  #pragma unroll
  for (int m = 1; m < 64; m <<= 1) s += __shfl_xor(s, m, 64);
  if (lane == 0) lamRow[row] = 2.0f / fmaxf(1.0f - s, EPSF);
}

// ---------------- kernel 2: column norms of z, cosh/sinh of 2*bias ----------------
__global__ __launch_bounds__(256) void col_stats_kernel(
    const float* __restrict__ zq, const float* __restrict__ zk, const float* __restrict__ zv,
    const float* __restrict__ bq, const float* __restrict__ bk, const float* __restrict__ bv,
    float* __restrict__ znA, float* __restrict__ chA, float* __restrict__ shA) {
  int mat = blockIdx.x >> 4;
  int c0 = (blockIdx.x & 15) * 64;
  const float* z = mat == 0 ? zq : (mat == 1 ? zk : zv);
  const float* bb = mat == 0 ? bq : (mat == 1 ? bk : bv);
  int col = c0 + (threadIdx.x & 63);
  int r0 = threadIdx.x >> 6;
  float s = 0.f;
  for (int rr = r0; rr < E_; rr += 4) {
    float t = z[(size_t)rr * E_ + col];
    s += t * t;
  }
  __shared__ float red[4][64];
  red[r0][threadIdx.x & 63] = s;
  __syncthreads();
  if (r0 == 0) {
    int l = threadIdx.x;
    s = red[0][l] + red[1][l] + red[2][l] + red[3][l];
    float n = fmaxf(sqrtf(s), 1e-15f);
    int idx = mat * E_ + col;
    znA[idx] = n;
    float rb = bb[col];
    chA[idx] = coshf(2.f * rb);
    shA[idx] = sinhf(2.f * rb);
  }
}

// ---------------- kernel 3: xz GEMM + hlinear epilogue (pre-normalization w) ----------------
__global__ __launch_bounds__(256) void hlinear_gemm_kernel(
    const float* __restrict__ xq, const float* __restrict__ xk, const float* __restrict__ xv,
    const float* __restrict__ zq, const float* __restrict__ zk, const float* __restrict__ zv,
    const float* __restrict__ lamRow, const float* __restrict__ znA,
    const float* __restrict__ chA, const float* __restrict__ shA,
    float* __restrict__ W) {
  const int mat = blockIdx.z;
  const float* x = mat == 0 ? xq : (mat == 1 ? xk : xv);
  const float* z = mat == 0 ? zq : (mat == 1 ? zk : zv);
  const int m0 = blockIdx.y * 128, n0 = blockIdx.x * 128;
  __shared__ float As[8][128];
  __shared__ float Bs[8][128];
  const int tid = threadIdx.x;
  const int tx = tid & 15, ty = tid >> 4;
  float acc[8][8];
  #pragma unroll
  for (int i = 0; i < 8; i++)
    #pragma unroll
    for (int j = 0; j < 8; j++) acc[i][j] = 0.f;
  const int arow = tid >> 1, acol = (tid & 1) * 4;
  const int brow = tid >> 5, bcol = (tid & 31) * 4;
  const float* aptr = x + (size_t)(m0 + arow) * E_ + acol;
  const float* bptr = z + (size_t)brow * E_ + n0 + bcol;
  for (int k0 = 0; k0 < E_; k0 += 8) {
    float4 av = *(const float4*)(aptr + k0);
    float4 bv = *(const float4*)(bptr + (size_t)k0 * E_);
    __syncthreads();
    As[acol + 0][arow] = av.x;
    As[acol + 1][arow] = av.y;
    As[acol + 2][arow] = av.z;
    As[acol + 3][arow] = av.w;
    *(float4*)&Bs[brow][bcol] = bv;
    __syncthreads();
    #pragma unroll
    for (int k = 0; k < 8; k++) {
      float4 a0 = *(const float4*)&As[k][ty * 4];
      float4 a1 = *(const float4*)&As[k][64 + ty * 4];
      float4 b0 = *(const float4*)&Bs[k][tx * 4];
      float4 b1 = *(const float4*)&Bs[k][64 + tx * 4];
      float a[8] = {a0.x, a0.y, a0.z, a0.w, a1.x, a1.y, a1.z, a1.w};
      float bb[8] = {b0.x, b0.y, b0.z, b0.w, b1.x, b1.y, b1.z, b1.w};
      #pragma unroll
      for (int i = 0; i < 8; i++)
        #pragma unroll
        for (int j = 0; j < 8; j++) acc[i][j] += a[i] * bb[j];
    }
  }
  const float* lamP = lamRow + mat * BS_ + m0;
  const int cbase = mat * E_ + n0;
  float* out = W + (size_t)mat * BS_ * E_;
  #pragma unroll
  for (int i = 0; i < 8; i++) {
    int mr = (i < 4) ? ty * 4 + i : 64 + ty * 4 + (i - 4);
    float lam = lamP[mr];
    #pragma unroll
    for (int j = 0; j < 8; j++) {
      int nc = (j < 4) ? tx * 4 + j : 64 + tx * 4 + (j - 4);
      float zn = znA[cbase + nc];
      float arg = lam * acc[i][j] / zn * chA[cbase + nc] - (lam - 1.f) * shA[cbase + nc];
      float v = 2.f * zn * asinhf(arg);
      out[(size_t)(m0 + mr) * E_ + (n0 + nc)] = sinhf(v);
    }
  }
}

// ---------------- kernel 4: normalize -> bf16 P + per-head squared norms (from bf16 values) ----------------
__global__ __launch_bounds__(256) void normalize_kernel(
    const float* __restrict__ W, unsigned short* __restrict__ Pbf, float* __restrict__ HN) {
  const float* w = W + (size_t)blockIdx.x * E_;
  int tid = threadIdx.x;
  float4 v = ((const float4*)w)[tid];
  float s = v.x * v.x + v.y * v.y + v.z * v.z + v.w * v.w;
  #pragma unroll
  for (int m = 1; m < 64; m <<= 1) s += __shfl_xor(s, m, 64);
  __shared__ float red[4];
  if ((tid & 63) == 0) red[tid >> 6] = s;
  __syncthreads();
  s = red[0] + red[1] + red[2] + red[3];
  float t = 1.f / (1.f + sqrtf(1.f + s));
  unsigned short p0 = f2bf(v.x * t), p1 = f2bf(v.y * t), p2 = f2bf(v.z * t), p3 = f2bf(v.w * t);
  ushort4 pk; pk.x = p0; pk.y = p1; pk.z = p2; pk.w = p3;
  ((ushort4*)(Pbf + (size_t)blockIdx.x * E_))[tid] = pk;
  // head squared-norm from the bf16-ROUNDED values (keeps diff2 cancellation exact)
  float r0 = bf2f(p0), r1 = bf2f(p1), r2 = bf2f(p2), r3 = bf2f(p3);
  float hs = r0 * r0 + r1 * r1 + r2 * r2 + r3 * r3;
  hs += __shfl_xor(hs, 1, 64);
  hs += __shfl_xor(hs, 2, 64);
  hs += __shfl_xor(hs, 4, 64);
  hs += __shfl_xor(hs, 8, 64);
  if ((tid & 15) == 0) HN[(size_t)blockIdx.x * H_ + (tid >> 4)] = hs;
}

// ---------------- kernel 5: MFMA flash hyperbolic attention + midpoint + logmap0*scale ----------------
// grid (S/128, H, B), 512 threads = 8 waves, each wave owns 16 queries. K-tile = 64 keys.
__global__ __launch_bounds__(512) void attention_kernel(
    const unsigned short* __restrict__ Pbf, const float* __restrict__ HN,
    float* __restrict__ TV, float scale) {
  const int qt = blockIdx.x, h = blockIdx.y, b = blockIdx.z;
  const unsigned short* pq = Pbf;
  const unsigned short* pk = Pbf + (size_t)BS_ * E_;
  const unsigned short* pv = Pbf + (size_t)2 * BS_ * E_;
  const float* hnq = HN;
  const float* hnk = HN + (size_t)BS_ * H_;
  const float* hnv = HN + (size_t)2 * BS_ * H_;

  const int tid = threadIdx.x;
  const int wid = tid >> 6, lane = tid & 63;
  const int quad = lane >> 4, l16 = lane & 15;

  __shared__ unsigned short Kbf[64][72];     // [key][dim] bf16, +8 pad
  __shared__ unsigned short Vt[64][72];      // [dim][key] bf16 (lambda folded in)
  __shared__ unsigned short Pw[8][16][72];   // per-wave P round-trip [query][key]
  __shared__ float k2s[64], omk2s[64], lamMs[64];

  const int qrow0 = qt * 128 + wid * 16;
  // Q A-fragments, loaded once directly from global: A[m=l16][k=quad*8+j]
  const size_t qgrow = ((size_t)(b * S_ + qrow0 + l16)) * E_ + h * 64;
  bf16x8 aq0 = *(const bf16x8*)(pq + qgrow + quad * 8);
  bf16x8 aq1 = *(const bf16x8*)(pq + qgrow + 32 + quad * 8);
  // per-C/D-row q2 (rows quad*4+r)
  float q2r[4], omq2[4];
  #pragma unroll
  for (int r2 = 0; r2 < 4; r2++) {
    q2r[r2] = hnq[((size_t)(b * S_ + qrow0 + quad * 4 + r2)) * H_ + h];
    omq2[r2] = 1.f - q2r[r2];
  }

  float mrun[4] = {-INFINITY, -INFINITY, -INFINITY, -INFINITY};
  float dnm[4] = {0.f, 0.f, 0.f, 0.f};
  f32x4 accO[4];
  #pragma unroll
  for (int dt = 0; dt < 4; dt++) accO[dt] = (f32x4){0.f, 0.f, 0.f, 0.f};

  for (int kt = 0; kt < S_ / 64; ++kt) {
    __syncthreads();
    // ---- stage K tile (straight copy) ----
    {
      int row = tid >> 3, col = (tid & 7) * 8;
      const uint4* src = (const uint4*)(pk + ((size_t)(b * S_ + kt * 64 + row)) * E_ + h * 64 + col);
      *(uint4*)&Kbf[row][col] = *src;
    }
    // ---- per-key stats ----
    if (tid < 64) {
      float k2 = hnk[((size_t)(b * S_ + kt * 64 + tid)) * H_ + h];
      k2s[tid] = k2;
      omk2s[tid] = 1.f - k2;
      float v2 = hnv[((size_t)(b * S_ + kt * 64 + tid)) * H_ + h];
      lamMs[tid] = 2.f / fmaxf(1.f - v2, EPSF) - 1.f;
    }
    // ---- stage V transposed with lambda folded: Vt[dim][key] = lam_k * v ----
    {
      int key = tid & 63, dg = tid >> 6;
      float v2 = hnv[((size_t)(b * S_ + kt * 64 + key)) * H_ + h];
      float lam = 2.f / fmaxf(1.f - v2, EPSF);
      union { uint4 q; unsigned short u[8]; } vv;
      vv.q = *(const uint4*)(pv + ((size_t)(b * S_ + kt * 64 + key)) * E_ + h * 64 + dg * 8);
      #pragma unroll
      for (int d = 0; d < 8; d++)
        Vt[dg * 8 + d][key] = f2bf(bf2f(vv.u[d]) * lam);
    }
    __syncthreads();

    // ---- QK^T via MFMA + Poincare distance ----
    float sc[4][4];
    float tmax[4] = {-1e30f, -1e30f, -1e30f, -1e30f};
    #pragma unroll
    for (int nt = 0; nt < 4; nt++) {
      bf16x8 bk0 = *(const bf16x8*)&Kbf[nt * 16 + l16][quad * 8];
      bf16x8 bk1 = *(const bf16x8*)&Kbf[nt * 16 + l16][32 + quad * 8];
      f32x4 z = (f32x4){0.f, 0.f, 0.f, 0.f};
      f32x4 d0 = __builtin_amdgcn_mfma_f32_16x16x32_bf16(aq0, bk0, z, 0, 0, 0);
      d0 = __builtin_amdgcn_mfma_f32_16x16x32_bf16(aq1, bk1, d0, 0, 0, 0);
      float k2 = k2s[nt * 16 + l16], omk2 = omk2s[nt * 16 + l16];
      #pragma unroll
      for (int r2 = 0; r2 < 4; r2++) {
        float diff2 = fmaxf(q2r[r2] + k2 - 2.f * d0[r2], 0.f);
        float den = fmaxf(omq2[r2] * omk2, EPSF);
        float ach = fmaxf(1.f + 2.f * diff2 / den, 1.f + 1e-6f);
        float sv = -acoshf(ach);
        sc[nt][r2] = sv;
        tmax[r2] = fmaxf(tmax[r2], sv);
      }
    }
    // ---- online-softmax row max (reduce over 16 key-lanes) ----
    float alpha[4];
    #pragma unroll
    for (int r2 = 0; r2 < 4; r2++) {
      float t = tmax[r2];
      t = fmaxf(t, __shfl_xor(t, 1, 64));
      t = fmaxf(t, __shfl_xor(t, 2, 64));
      t = fmaxf(t, __shfl_xor(t, 4, 64));
      t = fmaxf(t, __shfl_xor(t, 8, 64));
      float m_new = fmaxf(mrun[r2], t);
      alpha[r2] = expf(mrun[r2] - m_new);   // 0 on first tile
      mrun[r2] = m_new;
    }
    // ---- e = exp(s - m), dnm partial, P -> LDS (C-layout to A-layout round-trip) ----
    float dloc[4] = {0.f, 0.f, 0.f, 0.f};
    #pragma unroll
    for (int nt = 0; nt < 4; nt++) {
      float lm = lamMs[nt * 16 + l16];
      #pragma unroll
      for (int r2 = 0; r2 < 4; r2++) {
        float e = expf(sc[nt][r2] - mrun[r2]);
        Pw[wid][quad * 4 + r2][nt * 16 + l16] = f2bf(e);
        dloc[r2] += e * lm;
      }
    }
    #pragma unroll
    for (int r2 = 0; r2 < 4; r2++) dnm[r2] = dnm[r2] * alpha[r2] + dloc[r2];
    // ---- rescale accumulator, PV via MFMA ----
    #pragma unroll
    for (int dt = 0; dt < 4; dt++)
      #pragma unroll
      for (int r2 = 0; r2 < 4; r2++) accO[dt][r2] *= alpha[r2];
    bf16x8 ap0 = *(const bf16x8*)&Pw[wid][l16][quad * 8];
    bf16x8 ap1 = *(const bf16x8*)&Pw[wid][l16][32 + quad * 8];
    #pragma unroll
    for (int dt = 0; dt < 4; dt++) {
      bf16x8 bv0 = *(const bf16x8*)&Vt[dt * 16 + l16][quad * 8];
      bf16x8 bv1 = *(const bf16x8*)&Vt[dt * 16 + l16][32 + quad * 8];
      accO[dt] = __builtin_amdgcn_mfma_f32_16x16x32_bf16(ap0, bv0, accO[dt], 0, 0, 0);
      accO[dt] = __builtin_amdgcn_mfma_f32_16x16x32_bf16(ap1, bv1, accO[dt], 0, 0, 0);
    }
  }

  // ---- finalize: u = num/dnm, midpoint halving, logmap0 * scale ----
  #pragma unroll
  for (int r2 = 0; r2 < 4; r2++) {
    float dsum = dnm[r2];
    dsum += __shfl_xor(dsum, 1, 64);
    dsum += __shfl_xor(dsum, 2, 64);
    dsum += __shfl_xor(dsum, 4, 64);
    dsum += __shfl_xor(dsum, 8, 64);
    float uu[4];
    float su = 0.f;
    #pragma unroll
    for (int dt = 0; dt < 4; dt++) { uu[dt] = accO[dt][r2] / dsum; su += uu[dt] * uu[dt]; }
    su += __shfl_xor(su, 1, 64);
    su += __shfl_xor(su, 2, 64);
    su += __shfl_xor(su, 4, 64);
    su += __shfl_xor(su, 8, 64);
    float g = 1.f / (1.f + sqrtf(fmaxf(1.f - su, EPSF)));
    float n2 = fmaxf(su * g * g, 1e-15f);
    float n = sqrtf(n2);
    float fac = atanhf(fminf(n, 1.f - 1e-6f)) / n * g * scale;
    size_t orow = ((size_t)(b * S_ + qrow0 + quad * 4 + r2)) * E_ + h * 64 + l16;
    #pragma unroll
    for (int dt = 0; dt < 4; dt++) TV[orow + dt * 16] = fac * uu[dt];
  }
}

// ---------------- kernel 6: expmap0 per full E-row, in-place on d_out ----------------
__global__ __launch_bounds__(256) void expmap_kernel(float* __restrict__ TV) {
  float* w = TV + (size_t)blockIdx.x * E_;
  int tid = threadIdx.x;
  float4 v = ((float4*)w)[tid];
  float s = v.x * v.x + v.y * v.y + v.z * v.z + v.w * v.w;
  #pragma unroll
  for (int m = 1; m < 64; m <<= 1) s += __shfl_xor(s, m, 64);
  __shared__ float red[4];
  if ((tid & 63) == 0) red[tid >> 6] = s;
  __syncthreads();
  s = red[0] + red[1] + red[2] + red[3];
  float n = sqrtf(fmaxf(s, 1e-15f));
  float f = tanhf(n) / n;
  v.x *= f; v.y *= f; v.z *= f; v.w *= f;
  ((float4*)w)[tid] = v;
}

extern "C" void kernel_launch(void* const* d_in, const int* in_sizes, int n_in,
                              void* d_out, int out_size, void* d_ws, size_t ws_size,
                              hipStream_t stream) {
  (void)in_sizes; (void)n_in; (void)out_size; (void)ws_size;
  const float* q  = (const float*)d_in[0];
  const float* k  = (const float*)d_in[1];
  const float* v  = (const float*)d_in[2];
  const float* zq = (const float*)d_in[3];
  const float* bq = (const float*)d_in[4];
  const float* zk = (const float*)d_in[5];
  const float* bk = (const float*)d_in[6];
  const float* zv = (const float*)d_in[7];
  const float* bv = (const float*)d_in[8];

  float* W            = (float*)d_ws;                              // 3*BS*E fp32  (50.3 MB)
  unsigned short* Pbf = (unsigned short*)(W + (size_t)3 * BS_ * E_); // 3*BS*E bf16 (25.2 MB)
  float* HN           = (float*)(Pbf + (size_t)3 * BS_ * E_);      // 3*BS*16 fp32
  float* lamRow       = HN + (size_t)3 * BS_ * H_;
  float* znA          = lamRow + 3 * BS_;
  float* chA          = znA + 3 * E_;
  float* shA          = chA + 3 * E_;
  float* out          = (float*)d_out;

  double lb1 = lgamma(E_ / 2.0) + lgamma(0.5) - lgamma(E_ / 2.0 + 0.5);
  double lb2 = lgamma(D_ / 2.0) + lgamma(0.5) - lgamma(D_ / 2.0 + 0.5);
  float scale = (float)exp(lb1 - lb2);

  hipLaunchKernelGGL(row_lam_kernel, dim3(3 * BS_ / 4), dim3(256), 0, stream, q, k, v, lamRow);
  hipLaunchKernelGGL(col_stats_kernel, dim3(48), dim3(256), 0, stream,
                     zq, zk, zv, bq, bk, bv, znA, chA, shA);
  hipLaunchKernelGGL(hlinear_gemm_kernel, dim3(E_ / 128, BS_ / 128, 3), dim3(256), 0, stream,
                     q, k, v, zq, zk, zv, lamRow, znA, chA, shA, W);
  hipLaunchKernelGGL(normalize_kernel, dim3(3 * BS_), dim3(256), 0, stream, W, Pbf, HN);
  hipLaunchKernelGGL(attention_kernel, dim3(S_ / 128, H_, B_), dim3(512), 0, stream, Pbf, HN, out, scale);
  hipLaunchKernelGGL(expmap_kernel, dim3(BS_), dim3(256), 0, stream, out);
}

// Round 3
// 728.975 us; speedup vs baseline: 1.8143x; 1.3902x over previous
//
#include <hip/hip_runtime.h>
#include <cmath>

#define EPSF 1e-7f

constexpr int B_ = 4, S_ = 1024, E_ = 1024, H_ = 16, D_ = 64;
constexpr int BS_ = B_ * S_;   // 4096 rows per matrix

typedef __attribute__((ext_vector_type(8))) short bf16x8;
typedef __attribute__((ext_vector_type(4))) float f32x4;

__device__ inline unsigned int fbits(float f) { union { float f; unsigned int u; } x; x.f = f; return x.u; }
__device__ inline float ubits(unsigned int u) { union { unsigned int u; float f; } x; x.u = u; return x.f; }

__device__ inline unsigned short f2bf(float f) {
  unsigned int u = fbits(f);
  unsigned int r = u + 0x7fffu + ((u >> 16) & 1u);   // RNE
  return (unsigned short)(r >> 16);
}
__device__ inline float bf2f(unsigned short h) { return ubits(((unsigned int)h) << 16); }

// pack two fp32 into two truncated-bf16 (hi parts) in one uint
__device__ inline unsigned int packhi(float a, float b) {
  return (fbits(a) >> 16) | (fbits(b) & 0xFFFF0000u);
}
// residual lo parts (a - trunc_bf16(a)), truncated to bf16, packed
__device__ inline unsigned int packlo(float a, float b) {
  float la = a - ubits(fbits(a) & 0xFFFF0000u);
  float lb = b - ubits(fbits(b) & 0xFFFF0000u);
  return (fbits(la) >> 16) | (fbits(lb) & 0xFFFF0000u);
}

// ---------------- kernel 1: per-row lambda of the three inputs ----------------
__global__ __launch_bounds__(256) void row_lam_kernel(
    const float* __restrict__ xq, const float* __restrict__ xk,
    const float* __restrict__ xv, float* __restrict__ lamRow) {
  int row = blockIdx.x * 4 + (threadIdx.x >> 6);
  int lane = threadIdx.x & 63;
  const float* x = (row < BS_) ? xq : (row < 2 * BS_ ? xk : xv);
  int r = row & (BS_ - 1);
  const float4* xr = (const float4*)(x + (size_t)r * E_);
  float s = 0.f;
  #pragma unroll
  for (int i = 0; i < 4; i++) {
    float4 t = xr[lane + i * 64];
    s += t.x * t.x + t.y * t.y + t.z * t.z + t.w * t.w;
  }
  #pragma unroll
  for (int m = 1; m < 64; m <<= 1) s += __shfl_xor(s, m, 64);
  if (lane == 0) lamRow[row] = 2.0f / fmaxf(1.0f - s, EPSF);
}

// ---------------- kernel 2: column norms of z, cosh/sinh of 2*bias ----------------
__global__ __launch_bounds__(256) void col_stats_kernel(
    const float* __restrict__ zq, const float* __restrict__ zk, const float* __restrict__ zv,
    const float* __restrict__ bq, const float* __restrict__ bk, const float* __restrict__ bv,
    float* __restrict__ znA, float* __restrict__ chA, float* __restrict__ shA) {
  int mat = blockIdx.x >> 4;
  int c0 = (blockIdx.x & 15) * 64;
  const float* z = mat == 0 ? zq : (mat == 1 ? zk : zv);
  const float* bb = mat == 0 ? bq : (mat == 1 ? bk : bv);
  int col = c0 + (threadIdx.x & 63);
  int r0 = threadIdx.x >> 6;
  float s = 0.f;
  for (int rr = r0; rr < E_; rr += 4) {
    float t = z[(size_t)rr * E_ + col];
    s += t * t;
  }
  __shared__ float red[4][64];
  red[r0][threadIdx.x & 63] = s;
  __syncthreads();
  if (r0 == 0) {
    int l = threadIdx.x;
    s = red[0][l] + red[1][l] + red[2][l] + red[3][l];
    float n = fmaxf(sqrtf(s), 1e-15f);
    int idx = mat * E_ + col;
    znA[idx] = n;
    float rb = bb[col];
    chA[idx] = coshf(2.f * rb);
    shA[idx] = sinhf(2.f * rb);
  }
}

// ---------------- kernel 2b: transpose + hi/lo split of z -> BT[n][k] bf16 ----------------
__global__ __launch_bounds__(256) void zsplit_kernel(
    const float* __restrict__ zq, const float* __restrict__ zk, const float* __restrict__ zv,
    unsigned short* __restrict__ BhiT, unsigned short* __restrict__ BloT) {
  const int mat = blockIdx.z;
  const float* z = mat == 0 ? zq : (mat == 1 ? zk : zv);
  const int k0 = blockIdx.y * 64, n0 = blockIdx.x * 64;
  __shared__ float t[64][65];
  const int tid = threadIdx.x;
  {
    int kr = tid >> 4, nc = (tid & 15) * 4;
    #pragma unroll
    for (int i = 0; i < 4; i++) {
      float4 vv = *(const float4*)(z + (size_t)(k0 + kr + i * 16) * E_ + n0 + nc);
      t[kr + i * 16][nc + 0] = vv.x;
      t[kr + i * 16][nc + 1] = vv.y;
      t[kr + i * 16][nc + 2] = vv.z;
      t[kr + i * 16][nc + 3] = vv.w;
    }
  }
  __syncthreads();
  int nr = tid >> 2, kc = (tid & 3) * 16;
  unsigned int ph[8], pl[8];
  #pragma unroll
  for (int p = 0; p < 8; p++) {
    float x0 = t[kc + 2 * p][nr], x1 = t[kc + 2 * p + 1][nr];
    ph[p] = packhi(x0, x1);
    pl[p] = packlo(x0, x1);
  }
  size_t off = (size_t)mat * E_ * E_ + (size_t)(n0 + nr) * E_ + k0 + kc;
  uint4* dh = (uint4*)(BhiT + off);
  uint4* dl = (uint4*)(BloT + off);
  dh[0] = make_uint4(ph[0], ph[1], ph[2], ph[3]);
  dh[1] = make_uint4(ph[4], ph[5], ph[6], ph[7]);
  dl[0] = make_uint4(pl[0], pl[1], pl[2], pl[3]);
  dl[1] = make_uint4(pl[4], pl[5], pl[6], pl[7]);
}

// ---------------- kernel 3: split-bf16 MFMA GEMM + hlinear epilogue ----------------
// 128x128 tile, BK=32, 256 threads = 4 waves (2x2 of 64x64), 48 MFMA / wave / K-tile
__global__ __launch_bounds__(256, 2) void hlinear_mfma_kernel(
    const float* __restrict__ xq, const float* __restrict__ xk, const float* __restrict__ xv,
    const unsigned short* __restrict__ BhiT, const unsigned short* __restrict__ BloT,
    const float* __restrict__ lamRow, const float* __restrict__ znA,
    const float* __restrict__ chA, const float* __restrict__ shA,
    float* __restrict__ W) {
  const int mat = blockIdx.z;
  const float* x = mat == 0 ? xq : (mat == 1 ? xk : xv);
  const unsigned short* bh = BhiT + (size_t)mat * E_ * E_;
  const unsigned short* bl = BloT + (size_t)mat * E_ * E_;
  const int m0 = blockIdx.y * 128, n0 = blockIdx.x * 128;

  __shared__ unsigned short Ah[128][40];   // +8 pad: 80B rows (16B-aligned, 2-way banks)
  __shared__ unsigned short Al[128][40];
  __shared__ unsigned short Bh[128][40];
  __shared__ unsigned short Bl[128][40];

  const int tid = threadIdx.x;
  const int wid = tid >> 6, lane = tid & 63, quad = lane >> 4, l16 = lane & 15;
  const int wm = (wid >> 1) * 64, wn = (wid & 1) * 64;

  f32x4 acc[4][4];
  #pragma unroll
  for (int i = 0; i < 4; i++)
    #pragma unroll
    for (int j = 0; j < 4; j++) acc[i][j] = (f32x4){0.f, 0.f, 0.f, 0.f};

  const int arow = tid >> 1, ahalf = (tid & 1) * 16;
  const float* aptr = x + (size_t)(m0 + arow) * E_ + ahalf;
  const unsigned short* bhptr = bh + (size_t)(n0 + arow) * E_ + ahalf;
  const unsigned short* blptr = bl + (size_t)(n0 + arow) * E_ + ahalf;

  // prefetch K-tile 0
  float4 Ar[4];
  uint4 Brh[2], Brl[2];
  #pragma unroll
  for (int i = 0; i < 4; i++) Ar[i] = *(const float4*)(aptr + i * 4);
  Brh[0] = *(const uint4*)(bhptr);     Brh[1] = *(const uint4*)(bhptr + 8);
  Brl[0] = *(const uint4*)(blptr);     Brl[1] = *(const uint4*)(blptr + 8);

  for (int kt = 0; kt < E_ / 32; ++kt) {
    __syncthreads();
    // stage current K-tile from regs (A: fp32 -> hi/lo bf16)
    unsigned int uh[8], ul[8];
    #pragma unroll
    for (int i = 0; i < 4; i++) {
      float4 f = Ar[i];
      uh[2 * i] = packhi(f.x, f.y); uh[2 * i + 1] = packhi(f.z, f.w);
      ul[2 * i] = packlo(f.x, f.y); ul[2 * i + 1] = packlo(f.z, f.w);
    }
    *(uint4*)&Ah[arow][ahalf]     = make_uint4(uh[0], uh[1], uh[2], uh[3]);
    *(uint4*)&Ah[arow][ahalf + 8] = make_uint4(uh[4], uh[5], uh[6], uh[7]);
    *(uint4*)&Al[arow][ahalf]     = make_uint4(ul[0], ul[1], ul[2], ul[3]);
    *(uint4*)&Al[arow][ahalf + 8] = make_uint4(ul[4], ul[5], ul[6], ul[7]);
    *(uint4*)&Bh[arow][ahalf]     = Brh[0];
    *(uint4*)&Bh[arow][ahalf + 8] = Brh[1];
    *(uint4*)&Bl[arow][ahalf]     = Brl[0];
    *(uint4*)&Bl[arow][ahalf + 8] = Brl[1];
    // prefetch next K-tile (latency hidden by MFMA phase)
    if (kt < E_ / 32 - 1) {
      int k0 = (kt + 1) * 32;
      #pragma unroll
      for (int i = 0; i < 4; i++) Ar[i] = *(const float4*)(aptr + k0 + i * 4);
      Brh[0] = *(const uint4*)(bhptr + k0);     Brh[1] = *(const uint4*)(bhptr + k0 + 8);
      Brl[0] = *(const uint4*)(blptr + k0);     Brl[1] = *(const uint4*)(blptr + k0 + 8);
    }
    __syncthreads();
    // fragments + MFMA
    bf16x8 ah[4], al[4];
    #pragma unroll
    for (int mt = 0; mt < 4; mt++) {
      ah[mt] = *(const bf16x8*)&Ah[wm + mt * 16 + l16][quad * 8];
      al[mt] = *(const bf16x8*)&Al[wm + mt * 16 + l16][quad * 8];
    }
    #pragma unroll
    for (int nt = 0; nt < 4; nt++) {
      bf16x8 bhf = *(const bf16x8*)&Bh[wn + nt * 16 + l16][quad * 8];
      bf16x8 blf = *(const bf16x8*)&Bl[wn + nt * 16 + l16][quad * 8];
      #pragma unroll
      for (int mt = 0; mt < 4; mt++) {
        acc[mt][nt] = __builtin_amdgcn_mfma_f32_16x16x32_bf16(ah[mt], bhf, acc[mt][nt], 0, 0, 0);
        acc[mt][nt] = __builtin_amdgcn_mfma_f32_16x16x32_bf16(ah[mt], blf, acc[mt][nt], 0, 0, 0);
        acc[mt][nt] = __builtin_amdgcn_mfma_f32_16x16x32_bf16(al[mt], bhf, acc[mt][nt], 0, 0, 0);
      }
    }
  }

  // ---- epilogue: arg = lam*xz*(ch/zn) - (lam-1)*sh ; w = sinh(2*zn*asinh(arg)) ----
  const float* lamP = lamRow + mat * BS_;
  float lamv[16];
  #pragma unroll
  for (int mt = 0; mt < 4; mt++)
    #pragma unroll
    for (int r = 0; r < 4; r++)
      lamv[mt * 4 + r] = lamP[m0 + wm + mt * 16 + quad * 4 + r];
  float* out = W + (size_t)mat * BS_ * E_;
  #pragma unroll
  for (int nt = 0; nt < 4; nt++) {
    int cg = n0 + wn + nt * 16 + l16;
    float zn = znA[mat * E_ + cg];
    float chzn = chA[mat * E_ + cg] / zn;
    float sh = shA[mat * E_ + cg];
    float tzn = 2.f * zn;
    #pragma unroll
    for (int mt = 0; mt < 4; mt++) {
      #pragma unroll
      for (int r = 0; r < 4; r++) {
        float lam = lamv[mt * 4 + r];
        float arg = fmaf(lam * acc[mt][nt][r], chzn, -(lam - 1.f) * sh);
        float sq = sqrtf(fmaf(arg, arg, 1.f));
        float v = tzn * __logf(arg + sq);
        float w = 0.5f * (__expf(v) - __expf(-v));
        out[(size_t)(m0 + wm + mt * 16 + quad * 4 + r) * E_ + cg] = w;
      }
    }
  }
}

// ---------------- kernel 4: normalize -> bf16 P + per-head squared norms (from bf16 values) ----------------
__global__ __launch_bounds__(256) void normalize_kernel(
    const float* __restrict__ W, unsigned short* __restrict__ Pbf, float* __restrict__ HN) {
  const float* w = W + (size_t)blockIdx.x * E_;
  int tid = threadIdx.x;
  float4 v = ((const float4*)w)[tid];
  float s = v.x * v.x + v.y * v.y + v.z * v.z + v.w * v.w;
  #pragma unroll
  for (int m = 1; m < 64; m <<= 1) s += __shfl_xor(s, m, 64);
  __shared__ float red[4];
  if ((tid & 63) == 0) red[tid >> 6] = s;
  __syncthreads();
  s = red[0] + red[1] + red[2] + red[3];
  float t = 1.f / (1.f + sqrtf(1.f + s));
  unsigned short p0 = f2bf(v.x * t), p1 = f2bf(v.y * t), p2 = f2bf(v.z * t), p3 = f2bf(v.w * t);
  ushort4 pk; pk.x = p0; pk.y = p1; pk.z = p2; pk.w = p3;
  ((ushort4*)(Pbf + (size_t)blockIdx.x * E_))[tid] = pk;
  float r0 = bf2f(p0), r1 = bf2f(p1), r2 = bf2f(p2), r3 = bf2f(p3);
  float hs = r0 * r0 + r1 * r1 + r2 * r2 + r3 * r3;
  hs += __shfl_xor(hs, 1, 64);
  hs += __shfl_xor(hs, 2, 64);
  hs += __shfl_xor(hs, 4, 64);
  hs += __shfl_xor(hs, 8, 64);
  if ((tid & 15) == 0) HN[(size_t)blockIdx.x * H_ + (tid >> 4)] = hs;
}

// ---------------- kernel 5: MFMA flash hyperbolic attention + midpoint + logmap0*scale ----------------
__global__ __launch_bounds__(512) void attention_kernel(
    const unsigned short* __restrict__ Pbf, const float* __restrict__ HN,
    float* __restrict__ TV, float scale) {
  const int qt = blockIdx.x, h = blockIdx.y, b = blockIdx.z;
  const unsigned short* pq = Pbf;
  const unsigned short* pk = Pbf + (size_t)BS_ * E_;
  const unsigned short* pv = Pbf + (size_t)2 * BS_ * E_;
  const float* hnq = HN;
  const float* hnk = HN + (size_t)BS_ * H_;
  const float* hnv = HN + (size_t)2 * BS_ * H_;

  const int tid = threadIdx.x;
  const int wid = tid >> 6, lane = tid & 63;
  const int quad = lane >> 4, l16 = lane & 15;

  __shared__ unsigned short Kbf[64][72];
  __shared__ unsigned short Vt[64][72];
  __shared__ unsigned short Pw[8][16][72];
  __shared__ float k2s[64], omk2s[64], lamMs[64];

  const int qrow0 = qt * 128 + wid * 16;
  const size_t qgrow = ((size_t)(b * S_ + qrow0 + l16)) * E_ + h * 64;
  bf16x8 aq0 = *(const bf16x8*)(pq + qgrow + quad * 8);
  bf16x8 aq1 = *(const bf16x8*)(pq + qgrow + 32 + quad * 8);
  float q2r[4], omq2[4];
  #pragma unroll
  for (int r2 = 0; r2 < 4; r2++) {
    q2r[r2] = hnq[((size_t)(b * S_ + qrow0 + quad * 4 + r2)) * H_ + h];
    omq2[r2] = 1.f - q2r[r2];
  }

  float mrun[4] = {-INFINITY, -INFINITY, -INFINITY, -INFINITY};
  float dnm[4] = {0.f, 0.f, 0.f, 0.f};
  f32x4 accO[4];
  #pragma unroll
  for (int dt = 0; dt < 4; dt++) accO[dt] = (f32x4){0.f, 0.f, 0.f, 0.f};

  for (int kt = 0; kt < S_ / 64; ++kt) {
    __syncthreads();
    {
      int row = tid >> 3, col = (tid & 7) * 8;
      const uint4* src = (const uint4*)(pk + ((size_t)(b * S_ + kt * 64 + row)) * E_ + h * 64 + col);
      *(uint4*)&Kbf[row][col] = *src;
    }
    if (tid < 64) {
      float k2 = hnk[((size_t)(b * S_ + kt * 64 + tid)) * H_ + h];
      k2s[tid] = k2;
      omk2s[tid] = 1.f - k2;
      float v2 = hnv[((size_t)(b * S_ + kt * 64 + tid)) * H_ + h];
      lamMs[tid] = 2.f / fmaxf(1.f - v2, EPSF) - 1.f;
    }
    {
      int key = tid & 63, dg = tid >> 6;
      float v2 = hnv[((size_t)(b * S_ + kt * 64 + key)) * H_ + h];
      float lam = 2.f / fmaxf(1.f - v2, EPSF);
      union { uint4 q; unsigned short u[8]; } vv;
      vv.q = *(const uint4*)(pv + ((size_t)(b * S_ + kt * 64 + key)) * E_ + h * 64 + dg * 8);
      #pragma unroll
      for (int d = 0; d < 8; d++)
        Vt[dg * 8 + d][key] = f2bf(bf2f(vv.u[d]) * lam);
    }
    __syncthreads();

    float sc[4][4];
    float tmax[4] = {-1e30f, -1e30f, -1e30f, -1e30f};
    #pragma unroll
    for (int nt = 0; nt < 4; nt++) {
      bf16x8 bk0 = *(const bf16x8*)&Kbf[nt * 16 + l16][quad * 8];
      bf16x8 bk1 = *(const bf16x8*)&Kbf[nt * 16 + l16][32 + quad * 8];
      f32x4 z = (f32x4){0.f, 0.f, 0.f, 0.f};
      f32x4 d0 = __builtin_amdgcn_mfma_f32_16x16x32_bf16(aq0, bk0, z, 0, 0, 0);
      d0 = __builtin_amdgcn_mfma_f32_16x16x32_bf16(aq1, bk1, d0, 0, 0, 0);
      float k2 = k2s[nt * 16 + l16], omk2 = omk2s[nt * 16 + l16];
      #pragma unroll
      for (int r2 = 0; r2 < 4; r2++) {
        float diff2 = fmaxf(q2r[r2] + k2 - 2.f * d0[r2], 0.f);
        float den = fmaxf(omq2[r2] * omk2, EPSF);
        float ach = fmaxf(1.f + 2.f * diff2 / den, 1.f + 1e-6f);
        float sv = -acoshf(ach);
        sc[nt][r2] = sv;
        tmax[r2] = fmaxf(tmax[r2], sv);
      }
    }
    float alpha[4];
    #pragma unroll
    for (int r2 = 0; r2 < 4; r2++) {
      float t = tmax[r2];
      t = fmaxf(t, __shfl_xor(t, 1, 64));
      t = fmaxf(t, __shfl_xor(t, 2, 64));
      t = fmaxf(t, __shfl_xor(t, 4, 64));
      t = fmaxf(t, __shfl_xor(t, 8, 64));
      float m_new = fmaxf(mrun[r2], t);
      alpha[r2] = expf(mrun[r2] - m_new);
      mrun[r2] = m_new;
    }
    float dloc[4] = {0.f, 0.f, 0.f, 0.f};
    #pragma unroll
    for (int nt = 0; nt < 4; nt++) {
      float lm = lamMs[nt * 16 + l16];
      #pragma unroll
      for (int r2 = 0; r2 < 4; r2++) {
        float e = expf(sc[nt][r2] - mrun[r2]);
        Pw[wid][quad * 4 + r2][nt * 16 + l16] = f2bf(e);
        dloc[r2] += e * lm;
      }
    }
    #pragma unroll
    for (int r2 = 0; r2 < 4; r2++) dnm[r2] = dnm[r2] * alpha[r2] + dloc[r2];
    #pragma unroll
    for (int dt = 0; dt < 4; dt++)
      #pragma unroll
      for (int r2 = 0; r2 < 4; r2++) accO[dt][r2] *= alpha[r2];
    bf16x8 ap0 = *(const bf16x8*)&Pw[wid][l16][quad * 8];
    bf16x8 ap1 = *(const bf16x8*)&Pw[wid][l16][32 + quad * 8];
    #pragma unroll
    for (int dt = 0; dt < 4; dt++) {
      bf16x8 bv0 = *(const bf16x8*)&Vt[dt * 16 + l16][quad * 8];
      bf16x8 bv1 = *(const bf16x8*)&Vt[dt * 16 + l16][32 + quad * 8];
      accO[dt] = __builtin_amdgcn_mfma_f32_16x16x32_bf16(ap0, bv0, accO[dt], 0, 0, 0);
      accO[dt] = __builtin_amdgcn_mfma_f32_16x16x32_bf16(ap1, bv1, accO[dt], 0, 0, 0);
    }
  }

  #pragma unroll
  for (int r2 = 0; r2 < 4; r2++) {
    float dsum = dnm[r2];
    dsum += __shfl_xor(dsum, 1, 64);
    dsum += __shfl_xor(dsum, 2, 64);
    dsum += __shfl_xor(dsum, 4, 64);
    dsum += __shfl_xor(dsum, 8, 64);
    float uu[4];
    float su = 0.f;
    #pragma unroll
    for (int dt = 0; dt < 4; dt++) { uu[dt] = accO[dt][r2] / dsum; su += uu[dt] * uu[dt]; }
    su += __shfl_xor(su, 1, 64);
    su += __shfl_xor(su, 2, 64);
    su += __shfl_xor(su, 4, 64);
    su += __shfl_xor(su, 8, 64);
    float g = 1.f / (1.f + sqrtf(fmaxf(1.f - su, EPSF)));
    float n2 = fmaxf(su * g * g, 1e-15f);
    float n = sqrtf(n2);
    float fac = atanhf(fminf(n, 1.f - 1e-6f)) / n * g * scale;
    size_t orow = ((size_t)(b * S_ + qrow0 + quad * 4 + r2)) * E_ + h * 64 + l16;
    #pragma unroll
    for (int dt = 0; dt < 4; dt++) TV[orow + dt * 16] = fac * uu[dt];
  }
}

// ---------------- kernel 6: expmap0 per full E-row, in-place on d_out ----------------
__global__ __launch_bounds__(256) void expmap_kernel(float* __restrict__ TV) {
  float* w = TV + (size_t)blockIdx.x * E_;
  int tid = threadIdx.x;
  float4 v = ((float4*)w)[tid];
  float s = v.x * v.x + v.y * v.y + v.z * v.z + v.w * v.w;
  #pragma unroll
  for (int m = 1; m < 64; m <<= 1) s += __shfl_xor(s, m, 64);
  __shared__ float red[4];
  if ((tid & 63) == 0) red[tid >> 6] = s;
  __syncthreads();
  s = red[0] + red[1] + red[2] + red[3];
  float n = sqrtf(fmaxf(s, 1e-15f));
  float f = tanhf(n) / n;
  v.x *= f; v.y *= f; v.z *= f; v.w *= f;
  ((float4*)w)[tid] = v;
}

extern "C" void kernel_launch(void* const* d_in, const int* in_sizes, int n_in,
                              void* d_out, int out_size, void* d_ws, size_t ws_size,
                              hipStream_t stream) {
  (void)in_sizes; (void)n_in; (void)out_size; (void)ws_size;
  const float* q  = (const float*)d_in[0];
  const float* k  = (const float*)d_in[1];
  const float* v  = (const float*)d_in[2];
  const float* zq = (const float*)d_in[3];
  const float* bq = (const float*)d_in[4];
  const float* zk = (const float*)d_in[5];
  const float* bk = (const float*)d_in[6];
  const float* zv = (const float*)d_in[7];
  const float* bv = (const float*)d_in[8];

  float* W            = (float*)d_ws;                                // 3*BS*E fp32 (50.3 MB)
  unsigned short* Pbf = (unsigned short*)(W + (size_t)3 * BS_ * E_); // 3*BS*E bf16 (25.2 MB)
  // BhiT/BloT alias the Pbf region (dead until normalize_kernel runs after the GEMM)
  unsigned short* BhiT = Pbf;                                        // 3*E*E bf16 (6.3 MB)
  unsigned short* BloT = Pbf + (size_t)3 * E_ * E_;                  // 3*E*E bf16 (6.3 MB)
  float* HN           = (float*)(Pbf + (size_t)3 * BS_ * E_);        // 3*BS*16 fp32
  float* lamRow       = HN + (size_t)3 * BS_ * H_;
  float* znA          = lamRow + 3 * BS_;
  float* chA          = znA + 3 * E_;
  float* shA          = chA + 3 * E_;
  float* out          = (float*)d_out;

  double lb1 = lgamma(E_ / 2.0) + lgamma(0.5) - lgamma(E_ / 2.0 + 0.5);
  double lb2 = lgamma(D_ / 2.0) + lgamma(0.5) - lgamma(D_ / 2.0 + 0.5);
  float scale = (float)exp(lb1 - lb2);

  hipLaunchKernelGGL(row_lam_kernel, dim3(3 * BS_ / 4), dim3(256), 0, stream, q, k, v, lamRow);
  hipLaunchKernelGGL(col_stats_kernel, dim3(48), dim3(256), 0, stream,
                     zq, zk, zv, bq, bk, bv, znA, chA, shA);
  hipLaunchKernelGGL(zsplit_kernel, dim3(16, 16, 3), dim3(256), 0, stream, zq, zk, zv, BhiT, BloT);
  hipLaunchKernelGGL(hlinear_mfma_kernel, dim3(E_ / 128, BS_ / 128, 3), dim3(256), 0, stream,
                     q, k, v, BhiT, BloT, lamRow, znA, chA, shA, W);
  hipLaunchKernelGGL(normalize_kernel, dim3(3 * BS_), dim3(256), 0, stream, W, Pbf, HN);
  hipLaunchKernelGGL(attention_kernel, dim3(S_ / 128, H_, B_), dim3(512), 0, stream, Pbf, HN, out, scale);
  hipLaunchKernelGGL(expmap_kernel, dim3(BS_), dim3(256), 0, stream, out);
}

// Round 4
// 451.878 us; speedup vs baseline: 2.9268x; 1.6132x over previous
//
#include <hip/hip_runtime.h>
#include <cmath>

#define EPSF 1e-7f

constexpr int B_ = 4, S_ = 1024, E_ = 1024, H_ = 16, D_ = 64;
constexpr int BS_ = B_ * S_;   // 4096 rows per matrix

typedef __attribute__((ext_vector_type(8))) short bf16x8;
typedef __attribute__((ext_vector_type(4))) float f32x4;

__device__ inline unsigned int fbits(float f) { union { float f; unsigned int u; } x; x.f = f; return x.u; }
__device__ inline float ubits(unsigned int u) { union { unsigned int u; float f; } x; x.u = u; return x.f; }

__device__ inline unsigned short f2bf(float f) {
  unsigned int u = fbits(f);
  unsigned int r = u + 0x7fffu + ((u >> 16) & 1u);   // RNE
  return (unsigned short)(r >> 16);
}
__device__ inline float bf2f(unsigned short h) { return ubits(((unsigned int)h) << 16); }
__device__ inline float fastrcp(float x) { return __builtin_amdgcn_rcpf(x); }

// pack two fp32 into two truncated-bf16 (hi parts) in one uint
__device__ inline unsigned int packhi(float a, float b) {
  return (fbits(a) >> 16) | (fbits(b) & 0xFFFF0000u);
}
// residual lo parts (a - trunc_bf16(a)), truncated to bf16, packed
__device__ inline unsigned int packlo(float a, float b) {
  float la = a - ubits(fbits(a) & 0xFFFF0000u);
  float lb = b - ubits(fbits(b) & 0xFFFF0000u);
  return (fbits(la) >> 16) | (fbits(lb) & 0xFFFF0000u);
}

// ---------------- kernel 1: per-row lambda of the three inputs ----------------
__global__ __launch_bounds__(256) void row_lam_kernel(
    const float* __restrict__ xq, const float* __restrict__ xk,
    const float* __restrict__ xv, float* __restrict__ lamRow) {
  int row = blockIdx.x * 4 + (threadIdx.x >> 6);
  int lane = threadIdx.x & 63;
  const float* x = (row < BS_) ? xq : (row < 2 * BS_ ? xk : xv);
  int r = row & (BS_ - 1);
  const float4* xr = (const float4*)(x + (size_t)r * E_);
  float s = 0.f;
  #pragma unroll
  for (int i = 0; i < 4; i++) {
    float4 t = xr[lane + i * 64];
    s += t.x * t.x + t.y * t.y + t.z * t.z + t.w * t.w;
  }
  #pragma unroll
  for (int m = 1; m < 64; m <<= 1) s += __shfl_xor(s, m, 64);
  if (lane == 0) lamRow[row] = 2.0f / fmaxf(1.0f - s, EPSF);
}

// ---------------- kernel 2: column norms of z, cosh/sinh of 2*bias ----------------
__global__ __launch_bounds__(256) void col_stats_kernel(
    const float* __restrict__ zq, const float* __restrict__ zk, const float* __restrict__ zv,
    const float* __restrict__ bq, const float* __restrict__ bk, const float* __restrict__ bv,
    float* __restrict__ znA, float* __restrict__ chA, float* __restrict__ shA) {
  int mat = blockIdx.x >> 4;
  int c0 = (blockIdx.x & 15) * 64;
  const float* z = mat == 0 ? zq : (mat == 1 ? zk : zv);
  const float* bb = mat == 0 ? bq : (mat == 1 ? bk : bv);
  int col = c0 + (threadIdx.x & 63);
  int r0 = threadIdx.x >> 6;
  float s = 0.f;
  for (int rr = r0; rr < E_; rr += 4) {
    float t = z[(size_t)rr * E_ + col];
    s += t * t;
  }
  __shared__ float red[4][64];
  red[r0][threadIdx.x & 63] = s;
  __syncthreads();
  if (r0 == 0) {
    int l = threadIdx.x;
    s = red[0][l] + red[1][l] + red[2][l] + red[3][l];
    float n = fmaxf(sqrtf(s), 1e-15f);
    int idx = mat * E_ + col;
    znA[idx] = n;
    float rb = bb[col];
    chA[idx] = coshf(2.f * rb);
    shA[idx] = sinhf(2.f * rb);
  }
}

// ---------------- kernel 2b: transpose + hi/lo split of z -> BT[n][k] bf16 ----------------
__global__ __launch_bounds__(256) void zsplit_kernel(
    const float* __restrict__ zq, const float* __restrict__ zk, const float* __restrict__ zv,
    unsigned short* __restrict__ BhiT, unsigned short* __restrict__ BloT) {
  const int mat = blockIdx.z;
  const float* z = mat == 0 ? zq : (mat == 1 ? zk : zv);
  const int k0 = blockIdx.y * 64, n0 = blockIdx.x * 64;
  __shared__ float t[64][65];
  const int tid = threadIdx.x;
  {
    int kr = tid >> 4, nc = (tid & 15) * 4;
    #pragma unroll
    for (int i = 0; i < 4; i++) {
      float4 vv = *(const float4*)(z + (size_t)(k0 + kr + i * 16) * E_ + n0 + nc);
      t[kr + i * 16][nc + 0] = vv.x;
      t[kr + i * 16][nc + 1] = vv.y;
      t[kr + i * 16][nc + 2] = vv.z;
      t[kr + i * 16][nc + 3] = vv.w;
    }
  }
  __syncthreads();
  int nr = tid >> 2, kc = (tid & 3) * 16;
  unsigned int ph[8], pl[8];
  #pragma unroll
  for (int p = 0; p < 8; p++) {
    float x0 = t[kc + 2 * p][nr], x1 = t[kc + 2 * p + 1][nr];
    ph[p] = packhi(x0, x1);
    pl[p] = packlo(x0, x1);
  }
  size_t off = (size_t)mat * E_ * E_ + (size_t)(n0 + nr) * E_ + k0 + kc;
  uint4* dh = (uint4*)(BhiT + off);
  uint4* dl = (uint4*)(BloT + off);
  dh[0] = make_uint4(ph[0], ph[1], ph[2], ph[3]);
  dh[1] = make_uint4(ph[4], ph[5], ph[6], ph[7]);
  dl[0] = make_uint4(pl[0], pl[1], pl[2], pl[3]);
  dl[1] = make_uint4(pl[4], pl[5], pl[6], pl[7]);
}

// ---------------- kernel 3: split-bf16 MFMA GEMM + hlinear epilogue ----------------
__global__ __launch_bounds__(256, 2) void hlinear_mfma_kernel(
    const float* __restrict__ xq, const float* __restrict__ xk, const float* __restrict__ xv,
    const unsigned short* __restrict__ BhiT, const unsigned short* __restrict__ BloT,
    const float* __restrict__ lamRow, const float* __restrict__ znA,
    const float* __restrict__ chA, const float* __restrict__ shA,
    float* __restrict__ W) {
  const int mat = blockIdx.z;
  const float* x = mat == 0 ? xq : (mat == 1 ? xk : xv);
  const unsigned short* bh = BhiT + (size_t)mat * E_ * E_;
  const unsigned short* bl = BloT + (size_t)mat * E_ * E_;
  const int m0 = blockIdx.y * 128, n0 = blockIdx.x * 128;

  __shared__ unsigned short Ah[128][40];
  __shared__ unsigned short Al[128][40];
  __shared__ unsigned short Bh[128][40];
  __shared__ unsigned short Bl[128][40];

  const int tid = threadIdx.x;
  const int wid = tid >> 6, lane = tid & 63, quad = lane >> 4, l16 = lane & 15;
  const int wm = (wid >> 1) * 64, wn = (wid & 1) * 64;

  f32x4 acc[4][4];
  #pragma unroll
  for (int i = 0; i < 4; i++)
    #pragma unroll
    for (int j = 0; j < 4; j++) acc[i][j] = (f32x4){0.f, 0.f, 0.f, 0.f};

  const int arow = tid >> 1, ahalf = (tid & 1) * 16;
  const float* aptr = x + (size_t)(m0 + arow) * E_ + ahalf;
  const unsigned short* bhptr = bh + (size_t)(n0 + arow) * E_ + ahalf;
  const unsigned short* blptr = bl + (size_t)(n0 + arow) * E_ + ahalf;

  float4 Ar[4];
  uint4 Brh[2], Brl[2];
  #pragma unroll
  for (int i = 0; i < 4; i++) Ar[i] = *(const float4*)(aptr + i * 4);
  Brh[0] = *(const uint4*)(bhptr);     Brh[1] = *(const uint4*)(bhptr + 8);
  Brl[0] = *(const uint4*)(blptr);     Brl[1] = *(const uint4*)(blptr + 8);

  for (int kt = 0; kt < E_ / 32; ++kt) {
    __syncthreads();
    unsigned int uh[8], ul[8];
    #pragma unroll
    for (int i = 0; i < 4; i++) {
      float4 f = Ar[i];
      uh[2 * i] = packhi(f.x, f.y); uh[2 * i + 1] = packhi(f.z, f.w);
      ul[2 * i] = packlo(f.x, f.y); ul[2 * i + 1] = packlo(f.z, f.w);
    }
    *(uint4*)&Ah[arow][ahalf]     = make_uint4(uh[0], uh[1], uh[2], uh[3]);
    *(uint4*)&Ah[arow][ahalf + 8] = make_uint4(uh[4], uh[5], uh[6], uh[7]);
    *(uint4*)&Al[arow][ahalf]     = make_uint4(ul[0], ul[1], ul[2], ul[3]);
    *(uint4*)&Al[arow][ahalf + 8] = make_uint4(ul[4], ul[5], ul[6], ul[7]);
    *(uint4*)&Bh[arow][ahalf]     = Brh[0];
    *(uint4*)&Bh[arow][ahalf + 8] = Brh[1];
    *(uint4*)&Bl[arow][ahalf]     = Brl[0];
    *(uint4*)&Bl[arow][ahalf + 8] = Brl[1];
    if (kt < E_ / 32 - 1) {
      int k0 = (kt + 1) * 32;
      #pragma unroll
      for (int i = 0; i < 4; i++) Ar[i] = *(const float4*)(aptr + k0 + i * 4);
      Brh[0] = *(const uint4*)(bhptr + k0);     Brh[1] = *(const uint4*)(bhptr + k0 + 8);
      Brl[0] = *(const uint4*)(blptr + k0);     Brl[1] = *(const uint4*)(blptr + k0 + 8);
    }
    __syncthreads();
    bf16x8 ah[4], al[4];
    #pragma unroll
    for (int mt = 0; mt < 4; mt++) {
      ah[mt] = *(const bf16x8*)&Ah[wm + mt * 16 + l16][quad * 8];
      al[mt] = *(const bf16x8*)&Al[wm + mt * 16 + l16][quad * 8];
    }
    #pragma unroll
    for (int nt = 0; nt < 4; nt++) {
      bf16x8 bhf = *(const bf16x8*)&Bh[wn + nt * 16 + l16][quad * 8];
      bf16x8 blf = *(const bf16x8*)&Bl[wn + nt * 16 + l16][quad * 8];
      #pragma unroll
      for (int mt = 0; mt < 4; mt++) {
        acc[mt][nt] = __builtin_amdgcn_mfma_f32_16x16x32_bf16(ah[mt], bhf, acc[mt][nt], 0, 0, 0);
        acc[mt][nt] = __builtin_amdgcn_mfma_f32_16x16x32_bf16(ah[mt], blf, acc[mt][nt], 0, 0, 0);
        acc[mt][nt] = __builtin_amdgcn_mfma_f32_16x16x32_bf16(al[mt], bhf, acc[mt][nt], 0, 0, 0);
      }
    }
  }

  const float* lamP = lamRow + mat * BS_;
  float lamv[16];
  #pragma unroll
  for (int mt = 0; mt < 4; mt++)
    #pragma unroll
    for (int r = 0; r < 4; r++)
      lamv[mt * 4 + r] = lamP[m0 + wm + mt * 16 + quad * 4 + r];
  float* out = W + (size_t)mat * BS_ * E_;
  #pragma unroll
  for (int nt = 0; nt < 4; nt++) {
    int cg = n0 + wn + nt * 16 + l16;
    float zn = znA[mat * E_ + cg];
    float chzn = chA[mat * E_ + cg] / zn;
    float sh = shA[mat * E_ + cg];
    float tzn = 2.f * zn;
    #pragma unroll
    for (int mt = 0; mt < 4; mt++) {
      #pragma unroll
      for (int r = 0; r < 4; r++) {
        float lam = lamv[mt * 4 + r];
        float arg = fmaf(lam * acc[mt][nt][r], chzn, -(lam - 1.f) * sh);
        float sq = sqrtf(fmaf(arg, arg, 1.f));
        float v = tzn * __logf(arg + sq);
        float w = 0.5f * (__expf(v) - __expf(-v));
        out[(size_t)(m0 + wm + mt * 16 + quad * 4 + r) * E_ + cg] = w;
      }
    }
  }
}

// ---------------- kernel 4: normalize -> bf16 P + per-head squared norms (from bf16 values) ----------------
__global__ __launch_bounds__(256) void normalize_kernel(
    const float* __restrict__ W, unsigned short* __restrict__ Pbf, float* __restrict__ HN) {
  const float* w = W + (size_t)blockIdx.x * E_;
  int tid = threadIdx.x;
  float4 v = ((const float4*)w)[tid];
  float s = v.x * v.x + v.y * v.y + v.z * v.z + v.w * v.w;
  #pragma unroll
  for (int m = 1; m < 64; m <<= 1) s += __shfl_xor(s, m, 64);
  __shared__ float red[4];
  if ((tid & 63) == 0) red[tid >> 6] = s;
  __syncthreads();
  s = red[0] + red[1] + red[2] + red[3];
  float t = 1.f / (1.f + sqrtf(1.f + s));
  unsigned short p0 = f2bf(v.x * t), p1 = f2bf(v.y * t), p2 = f2bf(v.z * t), p3 = f2bf(v.w * t);
  ushort4 pk; pk.x = p0; pk.y = p1; pk.z = p2; pk.w = p3;
  ((ushort4*)(Pbf + (size_t)blockIdx.x * E_))[tid] = pk;
  float r0 = bf2f(p0), r1 = bf2f(p1), r2 = bf2f(p2), r3 = bf2f(p3);
  float hs = r0 * r0 + r1 * r1 + r2 * r2 + r3 * r3;
  hs += __shfl_xor(hs, 1, 64);
  hs += __shfl_xor(hs, 2, 64);
  hs += __shfl_xor(hs, 4, 64);
  hs += __shfl_xor(hs, 8, 64);
  if ((tid & 15) == 0) HN[(size_t)blockIdx.x * H_ + (tid >> 4)] = hs;
}

// ---------------- kernel 5: MFMA flash hyperbolic attention ----------------
// softmax weight computed algebraically: exp(-acosh(1+t)) = 1/(1+t+sqrt(t(t+2)))
// -> no transcendentals, no online-softmax (weights in (0,1], normalizer cancels in num/dnm)
__global__ __launch_bounds__(512) void attention_kernel(
    const unsigned short* __restrict__ Pbf, const float* __restrict__ HN,
    float* __restrict__ TV, float scale) {
  const int qt = blockIdx.x, h = blockIdx.y, b = blockIdx.z;
  const unsigned short* pq = Pbf;
  const unsigned short* pk = Pbf + (size_t)BS_ * E_;
  const unsigned short* pv = Pbf + (size_t)2 * BS_ * E_;
  const float* hnq = HN;
  const float* hnk = HN + (size_t)BS_ * H_;
  const float* hnv = HN + (size_t)2 * BS_ * H_;

  const int tid = threadIdx.x;
  const int wid = tid >> 6, lane = tid & 63;
  const int quad = lane >> 4, l16 = lane & 15;

  __shared__ unsigned short Kbf[64][72];
  __shared__ unsigned short Vt[64][72];
  __shared__ unsigned short Pw[8][16][72];
  __shared__ float k2s[64], romk2s[64], lamLs[64];

  const int qrow0 = qt * 128 + wid * 16;
  const size_t qgrow = ((size_t)(b * S_ + qrow0 + l16)) * E_ + h * 64;
  bf16x8 aq0 = *(const bf16x8*)(pq + qgrow + quad * 8);
  bf16x8 aq1 = *(const bf16x8*)(pq + qgrow + 32 + quad * 8);
  float q2r[4], tromq2[4];
  #pragma unroll
  for (int r2 = 0; r2 < 4; r2++) {
    float q2 = hnq[((size_t)(b * S_ + qrow0 + quad * 4 + r2)) * H_ + h];
    q2r[r2] = q2;
    tromq2[r2] = 2.f * fastrcp(1.f - q2);
  }

  float aWL[4] = {0.f, 0.f, 0.f, 0.f};
  float aW[4]  = {0.f, 0.f, 0.f, 0.f};
  f32x4 accO[4];
  #pragma unroll
  for (int dt = 0; dt < 4; dt++) accO[dt] = (f32x4){0.f, 0.f, 0.f, 0.f};

  for (int kt = 0; kt < S_ / 64; ++kt) {
    __syncthreads();
    // ---- stage K tile ----
    {
      int row = tid >> 3, col = (tid & 7) * 8;
      const uint4* src = (const uint4*)(pk + ((size_t)(b * S_ + kt * 64 + row)) * E_ + h * 64 + col);
      *(uint4*)&Kbf[row][col] = *src;
    }
    // ---- per-key stats ----
    if (tid < 64) {
      float k2 = hnk[((size_t)(b * S_ + kt * 64 + tid)) * H_ + h];
      k2s[tid] = k2;
      romk2s[tid] = fastrcp(1.f - k2);
      float v2 = hnv[((size_t)(b * S_ + kt * 64 + tid)) * H_ + h];
      lamLs[tid] = 2.f / fmaxf(1.f - v2, EPSF);
    }
    // ---- stage V transposed (pure bf16 shuffle, lambda folded into P instead) ----
    {
      int key = tid & 63, dg = tid >> 6;
      union { uint4 q; unsigned short u[8]; } vv;
      vv.q = *(const uint4*)(pv + ((size_t)(b * S_ + kt * 64 + key)) * E_ + h * 64 + dg * 8);
      #pragma unroll
      for (int d = 0; d < 8; d++)
        Vt[dg * 8 + d][key] = vv.u[d];
    }
    __syncthreads();

    // ---- QK^T via MFMA + algebraic softmax weight ----
    #pragma unroll
    for (int nt = 0; nt < 4; nt++) {
      bf16x8 bk0 = *(const bf16x8*)&Kbf[nt * 16 + l16][quad * 8];
      bf16x8 bk1 = *(const bf16x8*)&Kbf[nt * 16 + l16][32 + quad * 8];
      f32x4 z = (f32x4){0.f, 0.f, 0.f, 0.f};
      f32x4 d0 = __builtin_amdgcn_mfma_f32_16x16x32_bf16(aq0, bk0, z, 0, 0, 0);
      d0 = __builtin_amdgcn_mfma_f32_16x16x32_bf16(aq1, bk1, d0, 0, 0, 0);
      float k2 = k2s[nt * 16 + l16];
      float romk2 = romk2s[nt * 16 + l16];
      float lamL = lamLs[nt * 16 + l16];
      #pragma unroll
      for (int r2 = 0; r2 < 4; r2++) {
        float diff2 = fmaf(-2.f, d0[r2], q2r[r2] + k2);
        float t = fmaxf(diff2 * (tromq2[r2] * romk2), 1e-6f);
        float w = fastrcp((1.f + t) + sqrtf(fmaf(t, t, t + t)));
        float wl = w * lamL;
        Pw[wid][quad * 4 + r2][nt * 16 + l16] = f2bf(wl);
        aWL[r2] += wl;
        aW[r2] += w;
      }
    }
    // ---- PV via MFMA (P holds w*lambda; wave-private LDS round-trip) ----
    bf16x8 ap0 = *(const bf16x8*)&Pw[wid][l16][quad * 8];
    bf16x8 ap1 = *(const bf16x8*)&Pw[wid][l16][32 + quad * 8];
    #pragma unroll
    for (int dt = 0; dt < 4; dt++) {
      bf16x8 bv0 = *(const bf16x8*)&Vt[dt * 16 + l16][quad * 8];
      bf16x8 bv1 = *(const bf16x8*)&Vt[dt * 16 + l16][32 + quad * 8];
      accO[dt] = __builtin_amdgcn_mfma_f32_16x16x32_bf16(ap0, bv0, accO[dt], 0, 0, 0);
      accO[dt] = __builtin_amdgcn_mfma_f32_16x16x32_bf16(ap1, bv1, accO[dt], 0, 0, 0);
    }
  }

  // ---- finalize: dnm = sum(w*lam) - sum(w); u = num/dnm; midpoint; logmap0*scale ----
  #pragma unroll
  for (int r2 = 0; r2 < 4; r2++) {
    float dsum = aWL[r2] - aW[r2];
    dsum += __shfl_xor(dsum, 1, 64);
    dsum += __shfl_xor(dsum, 2, 64);
    dsum += __shfl_xor(dsum, 4, 64);
    dsum += __shfl_xor(dsum, 8, 64);
    float uu[4];
    float su = 0.f;
    #pragma unroll
    for (int dt = 0; dt < 4; dt++) { uu[dt] = accO[dt][r2] / dsum; su += uu[dt] * uu[dt]; }
    su += __shfl_xor(su, 1, 64);
    su += __shfl_xor(su, 2, 64);
    su += __shfl_xor(su, 4, 64);
    su += __shfl_xor(su, 8, 64);
    float g = 1.f / (1.f + sqrtf(fmaxf(1.f - su, EPSF)));
    float n2 = fmaxf(su * g * g, 1e-15f);
    float n = sqrtf(n2);
    float fac = atanhf(fminf(n, 1.f - 1e-6f)) / n * g * scale;
    size_t orow = ((size_t)(b * S_ + qrow0 + quad * 4 + r2)) * E_ + h * 64 + l16;
    #pragma unroll
    for (int dt = 0; dt < 4; dt++) TV[orow + dt * 16] = fac * uu[dt];
  }
}

// ---------------- kernel 6: expmap0 per full E-row, in-place on d_out ----------------
__global__ __launch_bounds__(256) void expmap_kernel(float* __restrict__ TV) {
  float* w = TV + (size_t)blockIdx.x * E_;
  int tid = threadIdx.x;
  float4 v = ((float4*)w)[tid];
  float s = v.x * v.x + v.y * v.y + v.z * v.z + v.w * v.w;
  #pragma unroll
  for (int m = 1; m < 64; m <<= 1) s += __shfl_xor(s, m, 64);
  __shared__ float red[4];
  if ((tid & 63) == 0) red[tid >> 6] = s;
  __syncthreads();
  s = red[0] + red[1] + red[2] + red[3];
  float n = sqrtf(fmaxf(s, 1e-15f));
  float f = tanhf(n) / n;
  v.x *= f; v.y *= f; v.z *= f; v.w *= f;
  ((float4*)w)[tid] = v;
}

extern "C" void kernel_launch(void* const* d_in, const int* in_sizes, int n_in,
                              void* d_out, int out_size, void* d_ws, size_t ws_size,
                              hipStream_t stream) {
  (void)in_sizes; (void)n_in; (void)out_size; (void)ws_size;
  const float* q  = (const float*)d_in[0];
  const float* k  = (const float*)d_in[1];
  const float* v  = (const float*)d_in[2];
  const float* zq = (const float*)d_in[3];
  const float* bq = (const float*)d_in[4];
  const float* zk = (const float*)d_in[5];
  const float* bk = (const float*)d_in[6];
  const float* zv = (const float*)d_in[7];
  const float* bv = (const float*)d_in[8];

  float* W            = (float*)d_ws;                                // 3*BS*E fp32 (50.3 MB)
  unsigned short* Pbf = (unsigned short*)(W + (size_t)3 * BS_ * E_); // 3*BS*E bf16 (25.2 MB)
  unsigned short* BhiT = Pbf;                                        // aliases Pbf (dead until normalize)
  unsigned short* BloT = Pbf + (size_t)3 * E_ * E_;
  float* HN           = (float*)(Pbf + (size_t)3 * BS_ * E_);        // 3*BS*16 fp32
  float* lamRow       = HN + (size_t)3 * BS_ * H_;
  float* znA          = lamRow + 3 * BS_;
  float* chA          = znA + 3 * E_;
  float* shA          = chA + 3 * E_;
  float* out          = (float*)d_out;

  double lb1 = lgamma(E_ / 2.0) + lgamma(0.5) - lgamma(E_ / 2.0 + 0.5);
  double lb2 = lgamma(D_ / 2.0) + lgamma(0.5) - lgamma(D_ / 2.0 + 0.5);
  float scale = (float)exp(lb1 - lb2);

  hipLaunchKernelGGL(row_lam_kernel, dim3(3 * BS_ / 4), dim3(256), 0, stream, q, k, v, lamRow);
  hipLaunchKernelGGL(col_stats_kernel, dim3(48), dim3(256), 0, stream,
                     zq, zk, zv, bq, bk, bv, znA, chA, shA);
  hipLaunchKernelGGL(zsplit_kernel, dim3(16, 16, 3), dim3(256), 0, stream, zq, zk, zv, BhiT, BloT);
  hipLaunchKernelGGL(hlinear_mfma_kernel, dim3(E_ / 128, BS_ / 128, 3), dim3(256), 0, stream,
                     q, k, v, BhiT, BloT, lamRow, znA, chA, shA, W);
  hipLaunchKernelGGL(normalize_kernel, dim3(3 * BS_), dim3(256), 0, stream, W, Pbf, HN);
  hipLaunchKernelGGL(attention_kernel, dim3(S_ / 128, H_, B_), dim3(512), 0, stream, Pbf, HN, out, scale);
  hipLaunchKernelGGL(expmap_kernel, dim3(BS_), dim3(256), 0, stream, out);
}